// Round 3
// baseline (127.574 us; speedup 1.0000x reference)
//
#include <hip/hip_runtime.h>
#include <hip/hip_bf16.h>

#define B_DIM 4096
#define I_DIM 2048
#define H_DIM 2048

typedef unsigned short u16;
typedef unsigned int u32;
typedef __attribute__((ext_vector_type(8))) short bf16x8;
typedef __attribute__((ext_vector_type(4))) float f32x4;
typedef __attribute__((ext_vector_type(4))) u32 u32x4;

// fp32 -> bf16 round-to-nearest-even (bits)
__device__ __forceinline__ u16 f2bf(float f) {
  unsigned u = __float_as_uint(f);
  u += 0x7fffu + ((u >> 16) & 1u);
  return (u16)(u >> 16);
}

__device__ __forceinline__ void gload_lds16(const void* g, void* l) {
  __builtin_amdgcn_global_load_lds(
      (const __attribute__((address_space(1))) void*)g,
      (__attribute__((address_space(3))) void*)l, 16, 0, 0);
}

// ---------------------------------------------------------------------------
// Kernel A: fp32->bf16 convert. xb[B,I]; AB[I,2H] interleaved (an,bn) pairs.
// ---------------------------------------------------------------------------
__global__ void convert_ew(const float* __restrict__ x, const float* __restrict__ an,
                           const float* __restrict__ bn, u16* __restrict__ xb,
                           u32* __restrict__ ab) {
  const long NX4 = (long)B_DIM * I_DIM / 4;
  const long NA4 = (long)I_DIM * H_DIM / 4;
  const long total = NX4 + NA4;
  for (long t = (long)blockIdx.x * blockDim.x + threadIdx.x; t < total;
       t += (long)gridDim.x * blockDim.x) {
    if (t < NX4) {
      float4 v = *(const float4*)(x + t * 4);
      ushort4 o;
      o.x = f2bf(v.x); o.y = f2bf(v.y); o.z = f2bf(v.z); o.w = f2bf(v.w);
      *(ushort4*)(xb + t * 4) = o;
    } else {
      long p = (t - NX4) * 4;
      float4 va = *(const float4*)(an + p);
      float4 vb = *(const float4*)(bn + p);
      u32x4 w;
      w.x = (u32)f2bf(va.x) | ((u32)f2bf(vb.x) << 16);
      w.y = (u32)f2bf(va.y) | ((u32)f2bf(vb.y) << 16);
      w.z = (u32)f2bf(va.z) | ((u32)f2bf(vb.z) << 16);
      w.w = (u32)f2bf(va.w) | ((u32)f2bf(vb.w) << 16);
      *(u32x4*)(ab + p) = w;  // ab[i*2H + 2h]=an, [..+1]=bn
    }
  }
}

// ---------------------------------------------------------------------------
// Kernel B: coeff [I,H] fp32 -> coeffT [H,I] bf16
// ---------------------------------------------------------------------------
__global__ void transpose_conv(const float* __restrict__ c, u16* __restrict__ ct) {
  __shared__ float tile[32][33];
  const int i0 = blockIdx.y * 32;
  const int h0 = blockIdx.x * 32;
  const int tx = threadIdx.x;
  const int ty = threadIdx.y;
  for (int r = ty; r < 32; r += 8)
    tile[r][tx] = c[(long)(i0 + r) * H_DIM + (h0 + tx)];
  __syncthreads();
  for (int r = ty; r < 32; r += 8)
    ct[(long)(h0 + r) * I_DIM + (i0 + tx)] = f2bf(tile[tx][r]);
}

// ---------------------------------------------------------------------------
// 4-phase pipelined GEMM. BM=256, BN=128, BK=64, 8 waves (4Mx2N), per-wave
// 64x64. Triple-buffered LDS (3 x 48KB), depth-2 prefetch spread across
// phases, counted vmcnt(6), XOR-swizzled LDS, setprio around MFMA clusters.
// ---------------------------------------------------------------------------
#define BUFSZ 49152
#define BOFF  32768  // B-tile offset within a buffer

__device__ __forceinline__ void stageA(const char* Ab, long kbyte, long lda,
                                       char* buf, int tid, int i) {
  const int o = i * 8192 + tid * 16;
  const int row = o >> 7;
  const int ls = ((((o >> 4) & 7) ^ (row & 7)) << 4);
  gload_lds16(Ab + (long)row * lda + kbyte + ls, buf + o);
}
__device__ __forceinline__ void stageB(const char* Bb, long kbyte, long ldb,
                                       char* buf, int tid, int i) {
  const int o = i * 8192 + tid * 16;
  const int row = o >> 7;
  const int ls = ((((o >> 4) & 7) ^ (row & 7)) << 4);
  gload_lds16(Bb + (long)row * ldb + kbyte + ls, buf + BOFF + o);
}

// read one 16B fragment at (row, logical 16B-slot) from swizzled LDS tile
__device__ __forceinline__ bf16x8 frag_ld(const char* S, int row, int slot) {
  return *(const bf16x8*)(S + row * 128 + ((slot ^ (row & 7)) << 4));
}

#define PH_SYNC asm volatile("s_waitcnt lgkmcnt(0)" ::: "memory"); \
                __builtin_amdgcn_sched_barrier(0)

__device__ __forceinline__ void gemm_kloop(const u16* __restrict__ A,
                                           const u16* __restrict__ Bt,
                                           int rowA0, int colB0, long K,
                                           char* smem, f32x4 acc[4][4]) {
  const int tid = threadIdx.x;
  const int lane = tid & 63;
  const int wid = tid >> 6;      // 0..7
  const int wr = wid >> 1;       // 0..3 (M)
  const int wc = wid & 1;        // 0..1 (N)
  const long lda = K * 2, ldb = K * 2;
  const char* Ab = (const char*)A + (long)rowA0 * lda;
  const char* Bb = (const char*)Bt + (long)colB0 * ldb;
  const int ar = wr * 64 + (lane & 15);
  const int br = wc * 64 + (lane & 15);
  const int hs = lane >> 4;      // 0..3
  const int nt = (int)(K >> 6);

  char* bR = smem;               // tile t   (read)
  char* bM = smem + BUFSZ;       // tile t+1 (landing)
  char* bW = smem + 2 * BUFSZ;   // tile t+2 (stage target)

  // prologue: stage tiles 0 and 1 (6 loads each)
#pragma unroll
  for (int i = 0; i < 4; ++i) stageA(Ab, 0, lda, bR, tid, i);
#pragma unroll
  for (int i = 0; i < 2; ++i) stageB(Bb, 0, ldb, bR, tid, i);
#pragma unroll
  for (int i = 0; i < 4; ++i) stageA(Ab, 128, lda, bM, tid, i);
#pragma unroll
  for (int i = 0; i < 2; ++i) stageB(Bb, 128, ldb, bM, tid, i);

  for (int t = 0; t < nt; ++t) {
    // tile t's 6 loads landed; tile t+1's 6 stay in flight
    if (t < nt - 1) asm volatile("s_waitcnt vmcnt(6)" ::: "memory");
    else            asm volatile("s_waitcnt vmcnt(0)" ::: "memory");
    __builtin_amdgcn_sched_barrier(0);
    __builtin_amdgcn_s_barrier();
    __builtin_amdgcn_sched_barrier(0);

    const long kb2 = (long)(t + 2) * 128;
    const bool st = (t + 2 < nt);
    bf16x8 af[4][2], bfr[4][2];

    // ---- phase 0: reads a0,a1,b0,b1; stage A0,A1; MFMA m01 x n01
#pragma unroll
    for (int m = 0; m < 2; ++m)
#pragma unroll
      for (int s = 0; s < 2; ++s) {
        af[m][s]  = frag_ld(bR, ar + m * 16, s * 4 + hs);
        bfr[m][s] = frag_ld(bR + BOFF, br + m * 16, s * 4 + hs);
      }
    if (st) { stageA(Ab, kb2, lda, bW, tid, 0); stageA(Ab, kb2, lda, bW, tid, 1); }
    __builtin_amdgcn_s_barrier();
    PH_SYNC;
    __builtin_amdgcn_s_setprio(1);
#pragma unroll
    for (int m = 0; m < 2; ++m)
#pragma unroll
      for (int n = 0; n < 2; ++n)
#pragma unroll
        for (int s = 0; s < 2; ++s)
          acc[m][n] = __builtin_amdgcn_mfma_f32_16x16x32_bf16(af[m][s], bfr[n][s],
                                                              acc[m][n], 0, 0, 0);
    __builtin_amdgcn_s_setprio(0);
    __builtin_amdgcn_s_barrier();

    // ---- phase 1: reads a2,a3; stage A2,A3; MFMA m23 x n01
#pragma unroll
    for (int m = 2; m < 4; ++m)
#pragma unroll
      for (int s = 0; s < 2; ++s)
        af[m][s] = frag_ld(bR, ar + m * 16, s * 4 + hs);
    if (st) { stageA(Ab, kb2, lda, bW, tid, 2); stageA(Ab, kb2, lda, bW, tid, 3); }
    __builtin_amdgcn_s_barrier();
    PH_SYNC;
    __builtin_amdgcn_s_setprio(1);
#pragma unroll
    for (int m = 2; m < 4; ++m)
#pragma unroll
      for (int n = 0; n < 2; ++n)
#pragma unroll
        for (int s = 0; s < 2; ++s)
          acc[m][n] = __builtin_amdgcn_mfma_f32_16x16x32_bf16(af[m][s], bfr[n][s],
                                                              acc[m][n], 0, 0, 0);
    __builtin_amdgcn_s_setprio(0);
    __builtin_amdgcn_s_barrier();

    // ---- phase 2: reads b2,b3; stage B0,B1; MFMA m23 x n23
#pragma unroll
    for (int n = 2; n < 4; ++n)
#pragma unroll
      for (int s = 0; s < 2; ++s)
        bfr[n][s] = frag_ld(bR + BOFF, br + n * 16, s * 4 + hs);
    if (st) { stageB(Bb, kb2, ldb, bW, tid, 0); stageB(Bb, kb2, ldb, bW, tid, 1); }
    __builtin_amdgcn_s_barrier();
    PH_SYNC;
    __builtin_amdgcn_s_setprio(1);
#pragma unroll
    for (int m = 2; m < 4; ++m)
#pragma unroll
      for (int n = 2; n < 4; ++n)
#pragma unroll
        for (int s = 0; s < 2; ++s)
          acc[m][n] = __builtin_amdgcn_mfma_f32_16x16x32_bf16(af[m][s], bfr[n][s],
                                                              acc[m][n], 0, 0, 0);
    __builtin_amdgcn_s_setprio(0);
    __builtin_amdgcn_s_barrier();

    // ---- phase 3: no reads; MFMA m01 x n23
    __builtin_amdgcn_s_setprio(1);
#pragma unroll
    for (int m = 0; m < 2; ++m)
#pragma unroll
      for (int n = 2; n < 4; ++n)
#pragma unroll
        for (int s = 0; s < 2; ++s)
          acc[m][n] = __builtin_amdgcn_mfma_f32_16x16x32_bf16(af[m][s], bfr[n][s],
                                                              acc[m][n], 0, 0, 0);
    __builtin_amdgcn_s_setprio(0);

    char* tmp = bR; bR = bM; bM = bW; bW = tmp;
  }
}

// XCD-aware bijective swizzle for a 256-block grid (16x16 tiles)
__device__ __forceinline__ void tile_coords(int& bm, int& bn) {
  const int bid = blockIdx.x;                 // 0..255, 256 % 8 == 0
  const int swz = (bid & 7) * 32 + (bid >> 3);
  bm = swz >> 4;
  bn = swz & 15;
}

// ---------------------------------------------------------------------------
// Kernel C: GEMM1  phase = xb @ ct^T ; epilogue writes (cos,sin) into CS[B,2H]
// ---------------------------------------------------------------------------
__global__ __launch_bounds__(512, 2) void gemm_phase(const u16* __restrict__ xb,
                                                     const u16* __restrict__ ct,
                                                     u32* __restrict__ cs) {
  __shared__ __align__(16) char smem[3 * BUFSZ];
  int bm, bn;
  tile_coords(bm, bn);
  const int rowA0 = bm * 256;
  const int colB0 = bn * 128;
  f32x4 acc[4][4];
#pragma unroll
  for (int m = 0; m < 4; ++m)
#pragma unroll
    for (int n = 0; n < 4; ++n)
#pragma unroll
      for (int j = 0; j < 4; ++j) acc[m][n][j] = 0.0f;

  gemm_kloop(xb, ct, rowA0, colB0, 2048, smem, acc);

  const int lane = threadIdx.x & 63;
  const int wid = threadIdx.x >> 6;
  const int wr = wid >> 1, wc = wid & 1;
#pragma unroll
  for (int m = 0; m < 4; ++m) {
#pragma unroll
    for (int n = 0; n < 4; ++n) {
      const int col = colB0 + wc * 64 + n * 16 + (lane & 15);
#pragma unroll
      for (int j = 0; j < 4; ++j) {
        const int row = rowA0 + wr * 64 + m * 16 + (lane >> 4) * 4 + j;
        const float p = acc[m][n][j];
        const u32 w = (u32)f2bf(__cosf(p)) | ((u32)f2bf(__sinf(p)) << 16);
        cs[(long)row * H_DIM + col] = w;
      }
    }
  }
}

// ---------------------------------------------------------------------------
// Kernel D: GEMM2  gain = CS[B,2H] @ AB[I,2H]^T + H*bias  (K=4096, fp32 out)
// ---------------------------------------------------------------------------
__global__ __launch_bounds__(512, 2) void gemm_gain(const u16* __restrict__ cs,
                                                    const u16* __restrict__ ab,
                                                    const float* __restrict__ bias,
                                                    float* __restrict__ out) {
  __shared__ __align__(16) char smem[3 * BUFSZ];
  int bm, bn;
  tile_coords(bm, bn);
  const int rowA0 = bm * 256;
  const int colB0 = bn * 128;
  f32x4 acc[4][4];
#pragma unroll
  for (int m = 0; m < 4; ++m)
#pragma unroll
    for (int n = 0; n < 4; ++n)
#pragma unroll
      for (int j = 0; j < 4; ++j) acc[m][n][j] = 0.0f;

  gemm_kloop(cs, ab, rowA0, colB0, 4096, smem, acc);

  const int lane = threadIdx.x & 63;
  const int wid = threadIdx.x >> 6;
  const int wr = wid >> 1, wc = wid & 1;
#pragma unroll
  for (int m = 0; m < 4; ++m) {
#pragma unroll
    for (int n = 0; n < 4; ++n) {
      const int col = colB0 + wc * 64 + n * 16 + (lane & 15);
      const float bv = 2048.0f * bias[col];
#pragma unroll
      for (int j = 0; j < 4; ++j) {
        const int row = rowA0 + wr * 64 + m * 16 + (lane >> 4) * 4 + j;
        out[(long)row * I_DIM + col] = acc[m][n][j] + bv;
      }
    }
  }
}

// ---------------------------------------------------------------------------
extern "C" void kernel_launch(void* const* d_in, const int* in_sizes, int n_in,
                              void* d_out, int out_size, void* d_ws, size_t ws_size,
                              hipStream_t stream) {
  const float* x     = (const float*)d_in[0];
  const float* coeff = (const float*)d_in[1];
  const float* an    = (const float*)d_in[2];
  const float* bn    = (const float*)d_in[3];
  const float* bias  = (const float*)d_in[4];
  float* out = (float*)d_out;

  char* ws = (char*)d_ws;
  u16* xb = (u16*)(ws);                  // 16 MB  [B,I] bf16
  u16* ct = (u16*)(ws + (16L << 20));    //  8 MB  [H,I] bf16 (coeff^T)
  u32* ab = (u32*)(ws + (24L << 20));    // 16 MB  [I,2H] bf16 interleaved (an,bn)
  u32* cs = (u32*)(ws + (40L << 20));    // 32 MB  [B,2H] bf16 interleaved (cos,sin)

  convert_ew<<<1024, 256, 0, stream>>>(x, an, bn, xb, ab);
  transpose_conv<<<dim3(H_DIM / 32, I_DIM / 32), dim3(32, 8), 0, stream>>>(coeff, ct);
  gemm_phase<<<256, 512, 0, stream>>>(xb, ct, cs);
  gemm_gain<<<256, 512, 0, stream>>>((const u16*)cs, (const u16*)ab, bias, out);
}